// Round 4
// baseline (96.860 us; speedup 1.0000x reference)
//
#include <hip/hip_runtime.h>

// Problem constants (from reference)
#define BSZ 128
#define NPTS 16384
#define GL 48
#define GW 20
#define GH 18
#define VOX_PER_B (GL * GW * GH)       // 17280 floats = 69120 B = 67.5 KB
#define NTOT (BSZ * NPTS)              // 2,097,152 points
#define BLOCK 512
#define NWAVES (BLOCK / 64)            // 8
#define BLOCKS_PER_BATCH 4
#define NBLK (BSZ * BLOCKS_PER_BATCH)             // 512 blocks -> 2 blocks/CU, 16 waves
#define PTS_PER_BLOCK (NPTS / BLOCKS_PER_BATCH)   // 4096
#define GROUP_PTS 4                                // consecutive points per thread-group
#define VOX_BYTES (VOX_PER_B * 4)                  // 69120
#define FULL_CHUNKS (VOX_BYTES / 1024)             // 67 full 1-KiB wave chunks
#define TAIL_BYTES (VOX_BYTES - FULL_CHUNKS * 1024) // 512 B -> lanes 0..31

typedef float __attribute__((address_space(1))) gfloat;
typedef float __attribute__((address_space(3))) sfloat;

// One point's trilinear sample + huber. Math bit-identical to rounds 1-3
// (measured absmax 0.0).
__device__ __forceinline__ float point_loss(const float* __restrict__ vlds,
                                            float px, float py, float pz, float hg)
{
    const float x = px + 2.4f;          // LENGTH/2
    const float y = py + 1.0f;          // WIDTH/2
    const float z = pz + hg * 0.5f;

    const float xm = floorf(x / 0.1f);
    const float ym = floorf(y / 0.1f);
    const float zm = floorf(z / 0.1f);

    const float tx = (x - xm * 0.1f) * 10.0f;
    const float ty = (y - ym * 0.1f) * 10.0f;
    const float tz = (z - zm * 0.1f) * 10.0f;
    const float sx = 1.0f - tx, sy = 1.0f - ty, sz = 1.0f - tz;

    const int xi0 = (int)fminf(fmaxf(xm,        0.0f), (float)(GL - 1));
    const int xi1 = (int)fminf(fmaxf(xm + 1.0f, 0.0f), (float)(GL - 1));
    const int yi0 = (int)fminf(fmaxf(ym,        0.0f), (float)(GW - 1));
    const int yi1 = (int)fminf(fmaxf(ym + 1.0f, 0.0f), (float)(GW - 1));

    // z as an adjacent pair: one ds_read2_b32 per (x,y) corner pair, with
    // branchless selects covering the z-clamp cases.
    const int  zb   = (int)fminf(fmaxf(zm, 0.0f), (float)(GH - 2));
    const bool z_hi = (zm >= (float)(GH - 1));
    const bool z_lo = (zm < 0.0f);

    const int ox0 = xi0 * (GW * GH);
    const int ox1 = xi1 * (GW * GH);
    const int oy0 = yi0 * GH;
    const int oy1 = yi1 * GH;

    const float* q11 = vlds + (ox1 + oy1 + zb);
    const float* q10 = vlds + (ox1 + oy0 + zb);
    const float* q01 = vlds + (ox0 + oy1 + zb);
    const float* q00 = vlds + (ox0 + oy0 + zb);

    float a11 = q11[0], b11 = q11[1];
    float a10 = q10[0], b10 = q10[1];
    float a01 = q01[0], b01 = q01[1];
    float a00 = q00[0], b00 = q00[1];

    const float v110 = z_hi ? b11 : a11;  const float v111 = z_lo ? a11 : b11;
    const float v100 = z_hi ? b10 : a10;  const float v101 = z_lo ? a10 : b10;
    const float v010 = z_hi ? b01 : a01;  const float v011 = z_lo ? a01 : b01;
    const float v000 = z_hi ? b00 : a00;  const float v001 = z_lo ? a00 : b00;

    const float sdf =
        (tx * ty) * (tz * v111 + sz * v110) +
        (tx * sy) * (tz * v101 + sz * v100) +
        (sx * ty) * (tz * v011 + sz * v010) +
        (sx * sy) * (tz * v001 + sz * v000);

    const float ax = fabsf(sdf);
    return (ax < 1.0f) ? 0.5f * sdf * sdf : ax - 0.5f;
}

__global__ __launch_bounds__(BLOCK, 4) void trilinear_huber_lds_kernel(
    const float* __restrict__ voxels,   // [B, GL, GW, GH]
    const float* __restrict__ pts,      // [B, N, 3]
    const float* __restrict__ hgt,      // [B, N]
    float* __restrict__ out)            // [1]
{
    __shared__ float vlds[VOX_PER_B];   // 67.5 KB (2 blocks/CU -> 135 KB < 160 KB)
    __shared__ float wsum[NWAVES];

    // XCD swizzle: the 4 blocks of one batch share blockIdx%8 (same XCD) so the
    // voxel slice is HBM-fetched once and L2-served 3x. Perf heuristic only.
    const int bid  = blockIdx.x;
    const int xcd  = bid & 7;
    const int rest = bid >> 3;          // [0, 64)
    const int slot = rest & 15;         // [0, 16)
    const int quar = rest >> 4;         // [0, 4)
    const int b    = xcd * 16 + slot;   // batch id [0, 128)
    const int tid  = threadIdx.x;
    const int lane = tid & 63;
    const int wid  = tid >> 6;

    // ---- Prefetch this thread's 8 points (2 groups of 4 consecutive) into
    // registers BEFORE staging, so the pts/hgt HBM stream overlaps the voxel
    // staging stream instead of starting after the barrier. ----
    const int pbase = b * NPTS + quar * PTS_PER_BLOCK;
    const int p0 = pbase + tid * GROUP_PTS;                      // group 0
    const int p1 = pbase + BLOCK * GROUP_PTS + tid * GROUP_PTS;  // group 1

    const float4* pp0 = (const float4*)(pts + 3 * (size_t)p0);   // 48 B aligned
    const float4 g0a = pp0[0], g0b = pp0[1], g0c = pp0[2];
    const float4 h0  = *(const float4*)(hgt + p0);
    const float4* pp1 = (const float4*)(pts + 3 * (size_t)p1);
    const float4 g1a = pp1[0], g1b = pp1[1], g1c = pp1[2];
    const float4 h1  = *(const float4*)(hgt + p1);

    // ---- Stage batch voxel slice into LDS with global_load_lds width=16:
    // wave-uniform LDS base + lane*16 == contiguous 1-KiB chunk per issue,
    // which matches our flat layout exactly. No VGPR round-trip. ----
    {
        const char* gbase = (const char*)(voxels + (size_t)b * VOX_PER_B);
        char* lbase = (char*)vlds;
        #pragma unroll 3
        for (int c = wid; c < FULL_CHUNKS; c += NWAVES) {   // 67 chunks over 8 waves
            const gfloat* gp = (const gfloat*)(gbase + c * 1024 + lane * 16);
            sfloat* lp = (sfloat*)(lbase + c * 1024);
            __builtin_amdgcn_global_load_lds((const __attribute__((address_space(1))) unsigned int*)gp,
                                             (__attribute__((address_space(3))) unsigned int*)lp,
                                             16, 0, 0);
        }
        // 512 B tail: lanes 0..31 of wave 0
        if (wid == 0 && lane < TAIL_BYTES / 16) {
            const gfloat* gp = (const gfloat*)(gbase + FULL_CHUNKS * 1024 + lane * 16);
            sfloat* lp = (sfloat*)(lbase + FULL_CHUNKS * 1024);
            __builtin_amdgcn_global_load_lds((const __attribute__((address_space(1))) unsigned int*)gp,
                                             (__attribute__((address_space(3))) unsigned int*)lp,
                                             16, 0, 0);
        }
    }
    __syncthreads();

    // ---- Compute 8 points from registers + LDS ----
    float acc = 0.0f;
    acc += point_loss(vlds, g0a.x, g0a.y, g0a.z, h0.x);
    acc += point_loss(vlds, g0a.w, g0b.x, g0b.y, h0.y);
    acc += point_loss(vlds, g0b.z, g0b.w, g0c.x, h0.z);
    acc += point_loss(vlds, g0c.y, g0c.z, g0c.w, h0.w);
    acc += point_loss(vlds, g1a.x, g1a.y, g1a.z, h1.x);
    acc += point_loss(vlds, g1a.w, g1b.x, g1b.y, h1.y);
    acc += point_loss(vlds, g1b.z, g1b.w, g1c.x, h1.z);
    acc += point_loss(vlds, g1c.y, g1c.z, g1c.w, h1.w);

    // ---- wave-64 shuffle reduction, then block reduction, one atomic ----
    #pragma unroll
    for (int off = 32; off > 0; off >>= 1)
        acc += __shfl_down(acc, off, 64);

    if (lane == 0) wsum[wid] = acc;
    __syncthreads();

    if (tid == 0) {
        float bsum = 0.0f;
        #pragma unroll
        for (int w = 0; w < NWAVES; ++w) bsum += wsum[w];
        atomicAdd(out, bsum * (1.0f / (float)NTOT));
    }
}

extern "C" void kernel_launch(void* const* d_in, const int* in_sizes, int n_in,
                              void* d_out, int out_size, void* d_ws, size_t ws_size,
                              hipStream_t stream) {
    const float* voxels = (const float*)d_in[0];   // [B, 48, 20, 18]
    const float* pts    = (const float*)d_in[1];   // [B, N, 3]
    const float* hgt    = (const float*)d_in[2];   // [B, N]
    float* out = (float*)d_out;

    // d_out is poisoned to 0xAA before every timed replay — zero it in-graph.
    hipMemsetAsync(out, 0, sizeof(float), stream);

    trilinear_huber_lds_kernel<<<NBLK, BLOCK, 0, stream>>>(voxels, pts, hgt, out);
}

// Round 5
// 88.741 us; speedup vs baseline: 1.0915x; 1.0915x over previous
//
#include <hip/hip_runtime.h>

// Problem constants (from reference)
#define BSZ 128
#define NPTS 16384
#define GL 48
#define GW 20
#define GH 18
#define VOX_PER_B (GL * GW * GH)       // 17280 floats = 67.5 KB
#define NTOT (BSZ * NPTS)              // 2,097,152 points
#define BLOCK 512
#define NWAVES (BLOCK / 64)            // 8
#define BLOCKS_PER_BATCH 4
#define NBLK (BSZ * BLOCKS_PER_BATCH)             // 512 blocks -> 2 blocks/CU, 16 waves
#define PTS_PER_BLOCK (NPTS / BLOCKS_PER_BATCH)   // 4096
#define GROUP_PTS 4                                // consecutive points per thread-group
#define VEC4S (VOX_PER_B / 4)                      // 4320 float4s to stage
#define STAGE_FULL 8                               // 8*512 = 4096 full iterations
#define STAGE_TAIL (VEC4S - STAGE_FULL * BLOCK)    // 224-thread tail

// One point's trilinear sample + huber. Math bit-identical to rounds 1-3
// (measured absmax 0.0).
__device__ __forceinline__ float point_loss(const float* __restrict__ vlds,
                                            float px, float py, float pz, float hg)
{
    const float x = px + 2.4f;          // LENGTH/2
    const float y = py + 1.0f;          // WIDTH/2
    const float z = pz + hg * 0.5f;

    const float xm = floorf(x / 0.1f);
    const float ym = floorf(y / 0.1f);
    const float zm = floorf(z / 0.1f);

    const float tx = (x - xm * 0.1f) * 10.0f;
    const float ty = (y - ym * 0.1f) * 10.0f;
    const float tz = (z - zm * 0.1f) * 10.0f;
    const float sx = 1.0f - tx, sy = 1.0f - ty, sz = 1.0f - tz;

    const int xi0 = (int)fminf(fmaxf(xm,        0.0f), (float)(GL - 1));
    const int xi1 = (int)fminf(fmaxf(xm + 1.0f, 0.0f), (float)(GL - 1));
    const int yi0 = (int)fminf(fmaxf(ym,        0.0f), (float)(GW - 1));
    const int yi1 = (int)fminf(fmaxf(ym + 1.0f, 0.0f), (float)(GW - 1));

    // z as an adjacent pair: one ds_read2_b32 per (x,y) corner pair, with
    // branchless selects covering the z-clamp cases.
    const int  zb   = (int)fminf(fmaxf(zm, 0.0f), (float)(GH - 2));
    const bool z_hi = (zm >= (float)(GH - 1));
    const bool z_lo = (zm < 0.0f);

    const int ox0 = xi0 * (GW * GH);
    const int ox1 = xi1 * (GW * GH);
    const int oy0 = yi0 * GH;
    const int oy1 = yi1 * GH;

    const float* q11 = vlds + (ox1 + oy1 + zb);
    const float* q10 = vlds + (ox1 + oy0 + zb);
    const float* q01 = vlds + (ox0 + oy1 + zb);
    const float* q00 = vlds + (ox0 + oy0 + zb);

    float a11 = q11[0], b11 = q11[1];
    float a10 = q10[0], b10 = q10[1];
    float a01 = q01[0], b01 = q01[1];
    float a00 = q00[0], b00 = q00[1];

    const float v110 = z_hi ? b11 : a11;  const float v111 = z_lo ? a11 : b11;
    const float v100 = z_hi ? b10 : a10;  const float v101 = z_lo ? a10 : b10;
    const float v010 = z_hi ? b01 : a01;  const float v011 = z_lo ? a01 : b01;
    const float v000 = z_hi ? b00 : a00;  const float v001 = z_lo ? a00 : b00;

    const float sdf =
        (tx * ty) * (tz * v111 + sz * v110) +
        (tx * sy) * (tz * v101 + sz * v100) +
        (sx * ty) * (tz * v011 + sz * v010) +
        (sx * sy) * (tz * v001 + sz * v000);

    const float ax = fabsf(sdf);
    return (ax < 1.0f) ? 0.5f * sdf * sdf : ax - 0.5f;
}

__global__ __launch_bounds__(BLOCK, 4) void trilinear_huber_lds_kernel(
    const float* __restrict__ voxels,   // [B, GL, GW, GH]
    const float* __restrict__ pts,      // [B, N, 3]
    const float* __restrict__ hgt,      // [B, N]
    float* __restrict__ out)            // [1]
{
    __shared__ float vlds[VOX_PER_B];   // 67.5 KB (2 blocks/CU -> 135 KB < 160 KB)
    __shared__ float wsum[NWAVES];

    // XCD swizzle: the 4 blocks of one batch share blockIdx%8 (same XCD) so the
    // voxel slice is HBM-fetched once and L2-served 3x. Perf heuristic only.
    const int bid  = blockIdx.x;
    const int xcd  = bid & 7;
    const int rest = bid >> 3;          // [0, 64)
    const int slot = rest & 15;         // [0, 16)
    const int quar = rest >> 4;         // [0, 4)
    const int b    = xcd * 16 + slot;   // batch id [0, 128)
    const int tid  = threadIdx.x;
    const int lane = tid & 63;
    const int wid  = tid >> 6;

    const int pbase = b * NPTS + quar * PTS_PER_BLOCK;
    const int p0 = pbase + tid * GROUP_PTS;          // group 0 (4 consecutive pts)
    const int p1 = p0 + BLOCK * GROUP_PTS;           // group 1

    // ---- Pipeline stage A: prefetch group-0 points (16 VGPRs) so this HBM
    // stream flies concurrently with the voxel staging stream. ----
    const float4* pp0 = (const float4*)(pts + 3 * (size_t)p0);   // 48 B aligned
    const float4 g0a = pp0[0], g0b = pp0[1], g0c = pp0[2];
    const float4 h0  = *(const float4*)(hgt + p0);

    // ---- Stage batch voxel slice into LDS: fully-unrolled float4 copy so all
    // 8 global loads issue back-to-back before the ds_writes drain them. ----
    {
        const float4* vb4 = (const float4*)(voxels + (size_t)b * VOX_PER_B);
        float4* lds4 = (float4*)vlds;
        #pragma unroll
        for (int k = 0; k < STAGE_FULL; ++k)
            lds4[tid + k * BLOCK] = vb4[tid + k * BLOCK];
        if (tid < STAGE_TAIL)
            lds4[tid + STAGE_FULL * BLOCK] = vb4[tid + STAGE_FULL * BLOCK];
    }
    __syncthreads();

    // ---- Pipeline stage B: issue group-1 prefetch BEFORE computing group 0,
    // so the second pts load overlaps group-0 LDS/VALU work. ----
    const float4* pp1 = (const float4*)(pts + 3 * (size_t)p1);
    const float4 g1a = pp1[0], g1b = pp1[1], g1c = pp1[2];
    const float4 h1  = *(const float4*)(hgt + p1);

    float acc = 0.0f;
    acc += point_loss(vlds, g0a.x, g0a.y, g0a.z, h0.x);
    acc += point_loss(vlds, g0a.w, g0b.x, g0b.y, h0.y);
    acc += point_loss(vlds, g0b.z, g0b.w, g0c.x, h0.z);
    acc += point_loss(vlds, g0c.y, g0c.z, g0c.w, h0.w);
    acc += point_loss(vlds, g1a.x, g1a.y, g1a.z, h1.x);
    acc += point_loss(vlds, g1a.w, g1b.x, g1b.y, h1.y);
    acc += point_loss(vlds, g1b.z, g1b.w, g1c.x, h1.z);
    acc += point_loss(vlds, g1c.y, g1c.z, g1c.w, h1.w);

    // ---- wave-64 shuffle reduction, then block reduction, one atomic ----
    #pragma unroll
    for (int off = 32; off > 0; off >>= 1)
        acc += __shfl_down(acc, off, 64);

    if (lane == 0) wsum[wid] = acc;
    __syncthreads();

    if (tid == 0) {
        float bsum = 0.0f;
        #pragma unroll
        for (int w = 0; w < NWAVES; ++w) bsum += wsum[w];
        atomicAdd(out, bsum * (1.0f / (float)NTOT));
    }
}

extern "C" void kernel_launch(void* const* d_in, const int* in_sizes, int n_in,
                              void* d_out, int out_size, void* d_ws, size_t ws_size,
                              hipStream_t stream) {
    const float* voxels = (const float*)d_in[0];   // [B, 48, 20, 18]
    const float* pts    = (const float*)d_in[1];   // [B, N, 3]
    const float* hgt    = (const float*)d_in[2];   // [B, N]
    float* out = (float*)d_out;

    // d_out is poisoned to 0xAA before every timed replay — zero it in-graph.
    hipMemsetAsync(out, 0, sizeof(float), stream);

    trilinear_huber_lds_kernel<<<NBLK, BLOCK, 0, stream>>>(voxels, pts, hgt, out);
}

// Round 6
// 88.500 us; speedup vs baseline: 1.0945x; 1.0027x over previous
//
#include <hip/hip_runtime.h>

// Problem constants (from reference)
#define BSZ 128
#define NPTS 16384
#define GL 48
#define GW 20
#define GH 18
#define VOX_PER_B (GL * GW * GH)       // 17280 floats = 67.5 KB
#define NTOT (BSZ * NPTS)              // 2,097,152 points
#define BLOCK 512
#define NWAVES (BLOCK / 64)            // 8
#define BLOCKS_PER_BATCH 4
#define NBLK (BSZ * BLOCKS_PER_BATCH)             // 512 blocks -> 2 blocks/CU, 16 waves
#define PTS_PER_BLOCK (NPTS / BLOCKS_PER_BATCH)   // 4096
#define GROUP_PTS 4                                // consecutive points per thread-group
#define VEC4S (VOX_PER_B / 4)                      // 4320 float4s to stage
#define STAGE_FULL 8                               // 8*512 = 4096 full iterations
#define STAGE_TAIL (VEC4S - STAGE_FULL * BLOCK)    // 224-thread tail

__device__ __forceinline__ float clampf(float v, float lo, float hi) {
    return fminf(fmaxf(v, lo), hi);    // -> v_med3_f32
}

// One point's trilinear sample + huber, minimal-VALU form.
//  * No divides: coords pre-scaled by 10 (grid_res=0.1).
//  * Boundary handling folded into the weights: base index clamped to
//    [0, dim-2] so corner pair (b, b+1) always valid; weight t' =
//    med3(scaled - base, 0, 1) is exactly 0 / 1 in the clamped regions,
//    which reproduces the reference's both-corners-clamped semantics
//    exactly (weights sum to 1 on identical-index corners).
//  * 8 corners = 4 ds_read2_b32 at constant offsets from 2 addresses.
__device__ __forceinline__ float point_loss(const float* __restrict__ vlds,
                                            float px, float py, float pz, float hg)
{
    // scaled grid coords: (p + half)/0.1
    const float xs = fmaf(px, 10.0f, 24.0f);           // (px+2.4)*10
    const float ys = fmaf(py, 10.0f, 10.0f);           // (py+1.0)*10
    const float zs = fmaf(pz, 10.0f, hg * 5.0f);       // (pz+hg/2)*10

    const float xmf = floorf(xs);
    const float ymf = floorf(ys);
    const float zmf = floorf(zs);

    const float xbf = clampf(xmf, 0.0f, (float)(GL - 2));
    const float ybf = clampf(ymf, 0.0f, (float)(GW - 2));
    const float zbf = clampf(zmf, 0.0f, (float)(GH - 2));

    const float tx = clampf(xs - xbf, 0.0f, 1.0f);
    const float ty = clampf(ys - ybf, 0.0f, 1.0f);
    const float tz = clampf(zs - zbf, 0.0f, 1.0f);
    const float sx = 1.0f - tx, sy = 1.0f - ty, sz = 1.0f - tz;

    const int xb = (int)xbf;
    const int yb = (int)ybf;
    const int zb = (int)zbf;

    const float* q  = vlds + (xb * (GW * GH) + yb * GH + zb);
    const float* q2 = q + (GW * GH);                   // x+1 plane (+360 dwords)

    const float c000 = q[0],   c001 = q[1];            // ds_read2 (0,1)
    const float c010 = q[GH],  c011 = q[GH + 1];       // ds_read2 (18,19)
    const float c100 = q2[0],  c101 = q2[1];
    const float c110 = q2[GH], c111 = q2[GH + 1];

    // factored trilinear: 14 VALU
    const float p00 = fmaf(tz, c001, sz * c000);
    const float p01 = fmaf(tz, c011, sz * c010);
    const float p10 = fmaf(tz, c101, sz * c100);
    const float p11 = fmaf(tz, c111, sz * c110);
    const float py0 = fmaf(ty, p01, sy * p00);
    const float py1 = fmaf(ty, p11, sy * p10);
    const float sdf = fmaf(tx, py1, sx * py0);

    const float ax = fabsf(sdf);
    return (ax < 1.0f) ? 0.5f * sdf * sdf : ax - 0.5f;
}

__global__ __launch_bounds__(BLOCK, 4) void trilinear_huber_lds_kernel(
    const float* __restrict__ voxels,   // [B, GL, GW, GH]
    const float* __restrict__ pts,      // [B, N, 3]
    const float* __restrict__ hgt,      // [B, N]
    float* __restrict__ out)            // [1]
{
    __shared__ float vlds[VOX_PER_B];   // 67.5 KB (2 blocks/CU -> 135 KB < 160 KB)
    __shared__ float wsum[NWAVES];

    // XCD swizzle: the 4 blocks of one batch share blockIdx%8 (same XCD) so the
    // voxel slice is HBM-fetched once and L2-served 3x. Perf heuristic only.
    const int bid  = blockIdx.x;
    const int xcd  = bid & 7;
    const int rest = bid >> 3;          // [0, 64)
    const int slot = rest & 15;         // [0, 16)
    const int quar = rest >> 4;         // [0, 4)
    const int b    = xcd * 16 + slot;   // batch id [0, 128)
    const int tid  = threadIdx.x;
    const int lane = tid & 63;
    const int wid  = tid >> 6;

    const int pbase = b * NPTS + quar * PTS_PER_BLOCK;
    const int p0 = pbase + tid * GROUP_PTS;          // group 0 (4 consecutive pts)
    const int p1 = p0 + BLOCK * GROUP_PTS;           // group 1

    // Prefetch group-0 points so this HBM stream overlaps voxel staging.
    const float4* pp0 = (const float4*)(pts + 3 * (size_t)p0);   // 48 B aligned
    const float4 g0a = pp0[0], g0b = pp0[1], g0c = pp0[2];
    const float4 h0  = *(const float4*)(hgt + p0);

    // Stage batch voxel slice into LDS (fully-unrolled float4 copy).
    {
        const float4* vb4 = (const float4*)(voxels + (size_t)b * VOX_PER_B);
        float4* lds4 = (float4*)vlds;
        #pragma unroll
        for (int k = 0; k < STAGE_FULL; ++k)
            lds4[tid + k * BLOCK] = vb4[tid + k * BLOCK];
        if (tid < STAGE_TAIL)
            lds4[tid + STAGE_FULL * BLOCK] = vb4[tid + STAGE_FULL * BLOCK];
    }
    __syncthreads();

    // Issue group-1 prefetch before computing group 0.
    const float4* pp1 = (const float4*)(pts + 3 * (size_t)p1);
    const float4 g1a = pp1[0], g1b = pp1[1], g1c = pp1[2];
    const float4 h1  = *(const float4*)(hgt + p1);

    float acc = 0.0f;
    acc += point_loss(vlds, g0a.x, g0a.y, g0a.z, h0.x);
    acc += point_loss(vlds, g0a.w, g0b.x, g0b.y, h0.y);
    acc += point_loss(vlds, g0b.z, g0b.w, g0c.x, h0.z);
    acc += point_loss(vlds, g0c.y, g0c.z, g0c.w, h0.w);
    acc += point_loss(vlds, g1a.x, g1a.y, g1a.z, h1.x);
    acc += point_loss(vlds, g1a.w, g1b.x, g1b.y, h1.y);
    acc += point_loss(vlds, g1b.z, g1b.w, g1c.x, h1.z);
    acc += point_loss(vlds, g1c.y, g1c.z, g1c.w, h1.w);

    // wave-64 shuffle reduction, then block reduction, one atomic
    #pragma unroll
    for (int off = 32; off > 0; off >>= 1)
        acc += __shfl_down(acc, off, 64);

    if (lane == 0) wsum[wid] = acc;
    __syncthreads();

    if (tid == 0) {
        float bsum = 0.0f;
        #pragma unroll
        for (int w = 0; w < NWAVES; ++w) bsum += wsum[w];
        atomicAdd(out, bsum * (1.0f / (float)NTOT));
    }
}

extern "C" void kernel_launch(void* const* d_in, const int* in_sizes, int n_in,
                              void* d_out, int out_size, void* d_ws, size_t ws_size,
                              hipStream_t stream) {
    const float* voxels = (const float*)d_in[0];   // [B, 48, 20, 18]
    const float* pts    = (const float*)d_in[1];   // [B, N, 3]
    const float* hgt    = (const float*)d_in[2];   // [B, N]
    float* out = (float*)d_out;

    // d_out is poisoned to 0xAA before every timed replay — zero it in-graph.
    hipMemsetAsync(out, 0, sizeof(float), stream);

    trilinear_huber_lds_kernel<<<NBLK, BLOCK, 0, stream>>>(voxels, pts, hgt, out);
}

// Round 7
// 87.603 us; speedup vs baseline: 1.1057x; 1.0102x over previous
//
#include <hip/hip_runtime.h>

// Problem constants (from reference)
#define BSZ 128
#define NPTS 16384
#define GL 48
#define GW 20
#define GH 18
#define VOX_PER_B (GL * GW * GH)       // 17280 floats = 67.5 KB
#define NTOT (BSZ * NPTS)              // 2,097,152 points
#define BLOCK 1024
#define NWAVES (BLOCK / 64)            // 16
#define BLOCKS_PER_BATCH 2             // voxel HBM traffic = 2 x 8.85 MB by construction
#define NBLK (BSZ * BLOCKS_PER_BATCH)             // 256 blocks -> 1 block/CU, 16 waves
#define PTS_PER_BLOCK (NPTS / BLOCKS_PER_BATCH)   // 8192
#define GROUP_PTS 4                                // consecutive points per thread-group
#define VEC4S (VOX_PER_B / 4)                      // 4320 float4s to stage
#define STAGE_FULL 4                               // 4*1024 = 4096 full iterations
#define STAGE_TAIL (VEC4S - STAGE_FULL * BLOCK)    // 224-thread tail

__device__ __forceinline__ float clampf(float v, float lo, float hi) {
    return fminf(fmaxf(v, lo), hi);    // -> v_med3_f32
}

// One point's trilinear sample + huber, minimal-VALU form (see R6 notes):
// no divides, boundary cases folded into med3-clamped weights (exactly
// reproduces reference both-corners-clamped semantics; measured absmax 0.0),
// 8 corners = 4 ds_read2_b32 at constant offsets from 2 addresses.
__device__ __forceinline__ float point_loss(const float* __restrict__ vlds,
                                            float px, float py, float pz, float hg)
{
    const float xs = fmaf(px, 10.0f, 24.0f);           // (px+2.4)/0.1
    const float ys = fmaf(py, 10.0f, 10.0f);           // (py+1.0)/0.1
    const float zs = fmaf(pz, 10.0f, hg * 5.0f);       // (pz+hg/2)/0.1

    const float xbf = clampf(floorf(xs), 0.0f, (float)(GL - 2));
    const float ybf = clampf(floorf(ys), 0.0f, (float)(GW - 2));
    const float zbf = clampf(floorf(zs), 0.0f, (float)(GH - 2));

    const float tx = clampf(xs - xbf, 0.0f, 1.0f);
    const float ty = clampf(ys - ybf, 0.0f, 1.0f);
    const float tz = clampf(zs - zbf, 0.0f, 1.0f);
    const float sx = 1.0f - tx, sy = 1.0f - ty, sz = 1.0f - tz;

    const int xb = (int)xbf;
    const int yb = (int)ybf;
    const int zb = (int)zbf;

    const float* q  = vlds + (xb * (GW * GH) + yb * GH + zb);
    const float* q2 = q + (GW * GH);                   // x+1 plane

    const float c000 = q[0],   c001 = q[1];            // ds_read2 (0,1)
    const float c010 = q[GH],  c011 = q[GH + 1];       // ds_read2 (18,19)
    const float c100 = q2[0],  c101 = q2[1];
    const float c110 = q2[GH], c111 = q2[GH + 1];

    const float p00 = fmaf(tz, c001, sz * c000);
    const float p01 = fmaf(tz, c011, sz * c010);
    const float p10 = fmaf(tz, c101, sz * c100);
    const float p11 = fmaf(tz, c111, sz * c110);
    const float py0 = fmaf(ty, p01, sy * p00);
    const float py1 = fmaf(ty, p11, sy * p10);
    const float sdf = fmaf(tx, py1, sx * py0);

    const float ax = fabsf(sdf);
    return (ax < 1.0f) ? 0.5f * sdf * sdf : ax - 0.5f;
}

__global__ __launch_bounds__(BLOCK, 4) void trilinear_huber_lds_kernel(
    const float* __restrict__ voxels,   // [B, GL, GW, GH]
    const float* __restrict__ pts,      // [B, N, 3]
    const float* __restrict__ hgt,      // [B, N]
    float* __restrict__ out)            // [1]
{
    __shared__ float vlds[VOX_PER_B];   // 67.5 KB
    __shared__ float wsum[NWAVES];

    // Pair the two blocks of one batch mod 8 (possible same-XCD L2 bonus;
    // correctness/traffic no longer depend on it).
    const int bid  = blockIdx.x;
    const int xcd  = bid & 7;
    const int slot = (bid >> 3) & 15;
    const int half = bid >> 7;          // [0, 2)
    const int b    = xcd * 16 + slot;   // batch id [0, 128)
    const int tid  = threadIdx.x;
    const int lane = tid & 63;
    const int wid  = tid >> 6;

    const int pbase = b * NPTS + half * PTS_PER_BLOCK;
    const int p0 = pbase + tid * GROUP_PTS;          // group 0 (4 consecutive pts)
    const int p1 = p0 + BLOCK * GROUP_PTS;           // group 1

    // Prefetch group-0 points so this HBM stream overlaps voxel staging.
    const float4* pp0 = (const float4*)(pts + 3 * (size_t)p0);   // 48 B aligned
    const float4 g0a = pp0[0], g0b = pp0[1], g0c = pp0[2];
    const float4 h0  = *(const float4*)(hgt + p0);

    // Stage batch voxel slice into LDS (fully-unrolled float4 copy).
    {
        const float4* vb4 = (const float4*)(voxels + (size_t)b * VOX_PER_B);
        float4* lds4 = (float4*)vlds;
        #pragma unroll
        for (int k = 0; k < STAGE_FULL; ++k)
            lds4[tid + k * BLOCK] = vb4[tid + k * BLOCK];
        if (tid < STAGE_TAIL)
            lds4[tid + STAGE_FULL * BLOCK] = vb4[tid + STAGE_FULL * BLOCK];
    }
    __syncthreads();

    // Issue group-1 prefetch before computing group 0.
    const float4* pp1 = (const float4*)(pts + 3 * (size_t)p1);
    const float4 g1a = pp1[0], g1b = pp1[1], g1c = pp1[2];
    const float4 h1  = *(const float4*)(hgt + p1);

    float acc = 0.0f;
    acc += point_loss(vlds, g0a.x, g0a.y, g0a.z, h0.x);
    acc += point_loss(vlds, g0a.w, g0b.x, g0b.y, h0.y);
    acc += point_loss(vlds, g0b.z, g0b.w, g0c.x, h0.z);
    acc += point_loss(vlds, g0c.y, g0c.z, g0c.w, h0.w);
    acc += point_loss(vlds, g1a.x, g1a.y, g1a.z, h1.x);
    acc += point_loss(vlds, g1a.w, g1b.x, g1b.y, h1.y);
    acc += point_loss(vlds, g1b.z, g1b.w, g1c.x, h1.z);
    acc += point_loss(vlds, g1c.y, g1c.z, g1c.w, h1.w);

    // wave-64 shuffle reduction, then block reduction, one atomic
    #pragma unroll
    for (int off = 32; off > 0; off >>= 1)
        acc += __shfl_down(acc, off, 64);

    if (lane == 0) wsum[wid] = acc;
    __syncthreads();

    if (tid == 0) {
        float bsum = 0.0f;
        #pragma unroll
        for (int w = 0; w < NWAVES; ++w) bsum += wsum[w];
        atomicAdd(out, bsum * (1.0f / (float)NTOT));
    }
}

extern "C" void kernel_launch(void* const* d_in, const int* in_sizes, int n_in,
                              void* d_out, int out_size, void* d_ws, size_t ws_size,
                              hipStream_t stream) {
    const float* voxels = (const float*)d_in[0];   // [B, 48, 20, 18]
    const float* pts    = (const float*)d_in[1];   // [B, N, 3]
    const float* hgt    = (const float*)d_in[2];   // [B, N]
    float* out = (float*)d_out;

    // d_out is poisoned to 0xAA before every timed replay — zero it in-graph.
    hipMemsetAsync(out, 0, sizeof(float), stream);

    trilinear_huber_lds_kernel<<<NBLK, BLOCK, 0, stream>>>(voxels, pts, hgt, out);
}